// Round 7
// baseline (381.188 us; speedup 1.0000x reference)
//
#include <hip/hip_runtime.h>
#include <hip/hip_bf16.h>
#include <math.h>

#define N_  512
#define D_  384
#define H_  12
#define DK_ 32
#define P_  128

typedef short short8 __attribute__((ext_vector_type(8)));
typedef float f32x4  __attribute__((ext_vector_type(4)));

static __device__ __forceinline__ unsigned short f2bf(float f) {
    union { float f; unsigned int u; } v; v.f = f;
    unsigned int r = (v.u + 0x7FFFu + ((v.u >> 16) & 1u)) >> 16;  // RNE
    return (unsigned short)r;
}
static __device__ __forceinline__ float bf2f(unsigned short u) {
    union { unsigned int u; float f; } v; v.u = ((unsigned int)u) << 16;
    return v.f;
}
static __device__ __forceinline__ short2 pk2bf(float a, float b) {
    __hip_bfloat162 h = __float22bfloat162_rn(make_float2(a, b));
    return *(short2*)&h;
}
typedef union { short8 v; short2 h2[4]; } s8u;

// ---------------------------------------------------------------------------
// K0: pair-bias logits MFMA GEMM, 256 thr, no LDS.
// All 16 float4 loads per wave staged BEFORE any convert/MFMA (MLP fix).
// __launch_bounds__(256,4): VGPR cap 128 -> 8 blocks/CU.
// ---------------------------------------------------------------------------
__global__ __launch_bounds__(256, 4) void k_pair(
    const float* __restrict__ x2d, const float* __restrict__ w_pb,
    float* __restrict__ pairlog)
{
    const int t    = threadIdx.x;
    const int wid  = t >> 6;
    const int lane = t & 63;
    const int quad = lane >> 4;
    const int col  = lane & 15;
    const float pair_w = 0.57735027f;

    // B fragments (w_pb), zero-padded h>=12
    short8 bfr[4];
    #pragma unroll
    for (int kt = 0; kt < 4; ++kt) {
        #pragma unroll
        for (int jj = 0; jj < 8; ++jj) {
            int p = kt * 32 + quad * 8 + jj;
            bfr[kt][jj] = (col < 12) ? (short)f2bf(w_pb[p * 12 + col]) : (short)0;
        }
    }

    // stage ALL loads for both tiles
    float4 xv[2][8];
    #pragma unroll
    for (int s = 0; s < 2; ++s) {
        const int T  = blockIdx.x * 8 + wid * 2 + s;
        const float* xrow = x2d + ((size_t)((T >> 5) * N_) + ((T & 31) << 4) + col) * P_;
        #pragma unroll
        for (int kt = 0; kt < 4; ++kt) {
            xv[s][kt * 2 + 0] = *(const float4*)(xrow + kt * 32 + quad * 8);
            xv[s][kt * 2 + 1] = *(const float4*)(xrow + kt * 32 + quad * 8 + 4);
        }
    }

    #pragma unroll
    for (int s = 0; s < 2; ++s) {
        const int T  = blockIdx.x * 8 + wid * 2 + s;
        const int i  = T >> 5;
        const int j0 = (T & 31) << 4;
        f32x4 acc = {0.f, 0.f, 0.f, 0.f};
        #pragma unroll
        for (int kt = 0; kt < 4; ++kt) {
            float4 f0 = xv[s][kt * 2 + 0];
            float4 f1 = xv[s][kt * 2 + 1];
            s8u afr;
            afr.h2[0] = pk2bf(f0.x, f0.y);
            afr.h2[1] = pk2bf(f0.z, f0.w);
            afr.h2[2] = pk2bf(f1.x, f1.y);
            afr.h2[3] = pk2bf(f1.z, f1.w);
            acc = __builtin_amdgcn_mfma_f32_16x16x32_bf16(afr.v, bfr[kt], acc, 0, 0, 0);
        }
        if (col < 12) {
            #pragma unroll
            for (int r = 0; r < 4; ++r) {
                int j = j0 + quad * 4 + r;
                pairlog[((size_t)(col * N_ + i)) * N_ + j] = pair_w * acc[r];
            }
        }
    }
}

// ---------------------------------------------------------------------------
// K1: projections + affine. Grid (64,5) as R5.
// ---------------------------------------------------------------------------
__global__ __launch_bounds__(384) void k_proj(
    const float* __restrict__ x1d, const float* __restrict__ pose_t,
    const float* __restrict__ pose_r,
    const float* __restrict__ w_sq, const float* __restrict__ w_sk,
    const float* __restrict__ w_sv, const float* __restrict__ w_pq,
    const float* __restrict__ w_pk, const float* __restrict__ w_pv,
    float* __restrict__ qs, float* __restrict__ kst,
    float* __restrict__ qp, float* __restrict__ kpt,
    unsigned short* __restrict__ vcatT)
{
    const int seg = blockIdx.y;
    const int i0  = blockIdx.x * 8;
    const int t   = threadIdx.x;

    __shared__ float raw[8][288];
    __shared__ float Rsh[8][9];
    __shared__ float Tsh[8][3];

    if (seg < 3) {
        const float* __restrict__ w = (seg == 0) ? w_sq : (seg == 1) ? w_sk : w_sv;
        float acc[8];
        #pragma unroll
        for (int r = 0; r < 8; ++r) acc[r] = 0.f;
        for (int d = 0; d < D_; d += 4) {
            float4 xr[8];
            #pragma unroll
            for (int r = 0; r < 8; ++r)
                xr[r] = *(const float4*)(x1d + (i0 + r) * D_ + d);
            #pragma unroll
            for (int e = 0; e < 4; ++e) {
                float wv = w[(d + e) * D_ + t];
                #pragma unroll
                for (int r = 0; r < 8; ++r)
                    acc[r] += ((const float*)&xr[r])[e] * wv;
            }
        }
        if (seg == 0) {
            #pragma unroll
            for (int r = 0; r < 8; ++r) qs[(i0 + r) * D_ + t] = acc[r];
        } else if (seg == 1) {
            *(float4*)(kst + t * N_ + i0)     = make_float4(acc[0], acc[1], acc[2], acc[3]);
            *(float4*)(kst + t * N_ + i0 + 4) = make_float4(acc[4], acc[5], acc[6], acc[7]);
        } else {
            int h = t >> 5, c = t & 31;
            s8u sv;
            #pragma unroll
            for (int r = 0; r < 4; ++r) sv.h2[r] = pk2bf(acc[2*r], acc[2*r+1]);
            *(short8*)(vcatT + ((size_t)h * 64 + c) * N_ + i0) = sv.v;
        }
    } else {
        if (t < 72) Rsh[t / 9][t % 9] = pose_r[(i0 + t / 9) * 9 + t % 9];
        else if (t < 96) {
            int r = (t - 72) / 3, c = (t - 72) % 3;
            Tsh[r][c] = pose_t[(i0 + r) * 3 + c];
        }

        if (t < 288) {
            const float* __restrict__ w;
            int col, ldw;
            if (seg == 3) {
                if (t < 144) { w = w_pq; col = t;       ldw = 144; }
                else         { w = w_pk; col = t - 144; ldw = 144; }
            } else         { w = w_pv; col = t;       ldw = 288; }
            float acc[8];
            #pragma unroll
            for (int r = 0; r < 8; ++r) acc[r] = 0.f;
            for (int d = 0; d < D_; d += 4) {
                float4 xr[8];
                #pragma unroll
                for (int r = 0; r < 8; ++r)
                    xr[r] = *(const float4*)(x1d + (i0 + r) * D_ + d);
                #pragma unroll
                for (int e = 0; e < 4; ++e) {
                    float wv = w[(d + e) * ldw + col];
                    #pragma unroll
                    for (int r = 0; r < 8; ++r)
                        acc[r] += ((const float*)&xr[r])[e] * wv;
                }
            }
            #pragma unroll
            for (int r = 0; r < 8; ++r) raw[r][t] = acc[r];
        }
        __syncthreads();

        if (t < 288) {
            const int x3   = t % 3;
            const int base = t - x3;
            if (seg == 3) {
                const int c = (t < 144) ? t : t - 144;
                if (t < 144) {
                    #pragma unroll
                    for (int r = 0; r < 8; ++r) {
                        float g = Rsh[r][0 + x3] * raw[r][base]
                                + Rsh[r][3 + x3] * raw[r][base + 1]
                                + Rsh[r][6 + x3] * raw[r][base + 2] + Tsh[r][x3];
                        qp[(i0 + r) * 144 + c] = g;
                    }
                } else {
                    float g[8];
                    #pragma unroll
                    for (int r = 0; r < 8; ++r)
                        g[r] = Rsh[r][0 + x3] * raw[r][base]
                             + Rsh[r][3 + x3] * raw[r][base + 1]
                             + Rsh[r][6 + x3] * raw[r][base + 2] + Tsh[r][x3];
                    *(float4*)(kpt + c * N_ + i0)     = make_float4(g[0], g[1], g[2], g[3]);
                    *(float4*)(kpt + c * N_ + i0 + 4) = make_float4(g[4], g[5], g[6], g[7]);
                }
            } else {
                int h = t / 24, pc = t % 24;
                float g[8];
                #pragma unroll
                for (int r = 0; r < 8; ++r)
                    g[r] = Rsh[r][0 + x3] * raw[r][base]
                         + Rsh[r][3 + x3] * raw[r][base + 1]
                         + Rsh[r][6 + x3] * raw[r][base + 2] + Tsh[r][x3];
                s8u sv;
                #pragma unroll
                for (int r = 0; r < 4; ++r) sv.h2[r] = pk2bf(g[2*r], g[2*r+1]);
                *(short8*)(vcatT + ((size_t)h * 64 + 32 + pc) * N_ + i0) = sv.v;
            }
        }
    }
}

// ---------------------------------------------------------------------------
// K2: sp logits + pair logits + softmax fused in registers -> bf16 attn only.
// ---------------------------------------------------------------------------
__global__ __launch_bounds__(256) void k_sp_soft(
    const float* __restrict__ qs, const float* __restrict__ kst,
    const float* __restrict__ qp, const float* __restrict__ kpt,
    const float* __restrict__ bias, const float* __restrict__ tpw,
    const float* __restrict__ pairlog,
    unsigned short* __restrict__ attn_bf)
{
    const int h  = blockIdx.x / 128;
    const int i0 = (blockIdx.x % 128) * 4;
    const int t  = threadIdx.x;
    const int lane = t & 63;
    const int wid  = t >> 6;
    __shared__ float qsh[4][32];
    __shared__ float qph[4][12];
    __shared__ float wredm[4][4];
    __shared__ float wreds[4][4];
    if (t < 128) { int il = t / 32, c = t % 32; qsh[il][c] = qs[(i0+il) * D_ + h*32 + c]; }
    else if (t < 176) { int r = t - 128; int il = r / 12, c = r % 12; qph[il][c] = qp[(i0+il)*144 + h*12 + c]; }
    const float pwh = 0.13608276f * log1pf(expf(tpw[h]));
    const float scalar_w = 0.10206207f;
    __syncthreads();

    float v[4][2];
    for (int jh = 0; jh < 2; ++jh) {
        int j = t + jh * 256;
        float kv[32];
        #pragma unroll
        for (int c = 0; c < 32; ++c) kv[c] = kst[(h*32 + c) * N_ + j];
        float kp[12];
        #pragma unroll
        for (int c = 0; c < 12; ++c) kp[c] = kpt[(h*12 + c) * N_ + j];

        #pragma unroll
        for (int il = 0; il < 4; ++il) {
            float s = 0.f;
            #pragma unroll
            for (int c = 0; c < 32; ++c) s += qsh[il][c] * kv[c];
            float dsum = 0.f;
            #pragma unroll
            for (int p = 0; p < 4; ++p) {
                float dx = qph[il][p*3+0] - kp[p*3+0];
                float dy = qph[il][p*3+1] - kp[p*3+1];
                float dz = qph[il][p*3+2] - kp[p*3+2];
                dsum += sqrtf(dx*dx + dy*dy + dz*dz);
            }
            v[il][jh] = scalar_w * s - 0.5f * pwh * dsum
                      + bias[(i0+il) * N_ + j]
                      + pairlog[((size_t)(h * N_ + (i0+il))) * N_ + j];
        }
    }

    #pragma unroll
    for (int il = 0; il < 4; ++il) {
        float mt = fmaxf(v[il][0], v[il][1]);
        #pragma unroll
        for (int off = 1; off < 64; off <<= 1)
            mt = fmaxf(mt, __shfl_xor(mt, off));
        if (lane == 0) wredm[il][wid] = mt;
    }
    __syncthreads();
    float m[4];
    #pragma unroll
    for (int il = 0; il < 4; ++il)
        m[il] = fmaxf(fmaxf(wredm[il][0], wredm[il][1]),
                      fmaxf(wredm[il][2], wredm[il][3]));

    #pragma unroll
    for (int il = 0; il < 4; ++il) {
        float e0 = __expf(v[il][0] - m[il]);
        float e1 = __expf(v[il][1] - m[il]);
        v[il][0] = e0; v[il][1] = e1;
        float st = e0 + e1;
        #pragma unroll
        for (int off = 1; off < 64; off <<= 1)
            st += __shfl_xor(st, off);
        if (lane == 0) wreds[il][wid] = st;
    }
    __syncthreads();
    #pragma unroll
    for (int il = 0; il < 4; ++il) {
        float inv = 1.0f / (wreds[il][0] + wreds[il][1] + wreds[il][2] + wreds[il][3]);
        size_t base = ((size_t)(h * N_ + i0 + il)) * N_;
        attn_bf[base + t]       = f2bf(v[il][0] * inv);
        attn_bf[base + t + 256] = f2bf(v[il][1] * inv);
    }
}

// ---------------------------------------------------------------------------
// K3 (merged): blocks 0..511 = tmp (8-deep staged x2d loads);
// blocks 512..895 = aggr (MFMA).
// ---------------------------------------------------------------------------
__global__ __launch_bounds__(256) void k_mid(
    const unsigned short* __restrict__ attn_bf,
    const float* __restrict__ x2d,
    const unsigned short* __restrict__ vcatT,
    float* __restrict__ tmp,
    float* __restrict__ feat, float* __restrict__ outpg)
{
    __shared__ float4 at[3][N_];
    __shared__ float red[4][1536];

    const int t = threadIdx.x;

    if (blockIdx.x < 512) {
        const int i = blockIdx.x;
        for (int idx = t; idx < 12 * N_; idx += 256) {
            int h = idx >> 9, j = idx & 511;
            float a = bf2f(attn_bf[((size_t)(h * N_ + i)) * N_ + j]);
            ((float*)&at[h >> 2][j])[h & 3] = a;
        }
        __syncthreads();

        const int p2 = (t & 63) * 2;
        const int jh = t >> 6;
        float acc[12][2];
        #pragma unroll
        for (int h = 0; h < 12; ++h) { acc[h][0] = 0.f; acc[h][1] = 0.f; }
        const float* xb = x2d + (size_t)i * N_ * P_ + p2;

        // 16 outer iters, 8 staged loads each (MLP)
        for (int j = jh; j < N_; j += 32) {
            float2 x[8];
            #pragma unroll
            for (int u = 0; u < 8; ++u)
                x[u] = *(const float2*)(xb + (j + u * 4) * P_);
            #pragma unroll
            for (int u = 0; u < 8; ++u) {
                int jj = j + u * 4;
                float4 a0 = at[0][jj], a1 = at[1][jj], a2 = at[2][jj];
                float xx = x[u].x, xy = x[u].y;
                acc[0][0]  += a0.x*xx; acc[0][1]  += a0.x*xy;
                acc[1][0]  += a0.y*xx; acc[1][1]  += a0.y*xy;
                acc[2][0]  += a0.z*xx; acc[2][1]  += a0.z*xy;
                acc[3][0]  += a0.w*xx; acc[3][1]  += a0.w*xy;
                acc[4][0]  += a1.x*xx; acc[4][1]  += a1.x*xy;
                acc[5][0]  += a1.y*xx; acc[5][1]  += a1.y*xy;
                acc[6][0]  += a1.z*xx; acc[6][1]  += a1.z*xy;
                acc[7][0]  += a1.w*xx; acc[7][1]  += a1.w*xy;
                acc[8][0]  += a2.x*xx; acc[8][1]  += a2.x*xy;
                acc[9][0]  += a2.y*xx; acc[9][1]  += a2.y*xy;
                acc[10][0] += a2.z*xx; acc[10][1] += a2.z*xy;
                acc[11][0] += a2.w*xx; acc[11][1] += a2.w*xy;
            }
        }
        #pragma unroll
        for (int h = 0; h < 12; ++h) {
            red[jh][h * 128 + p2]     = acc[h][0];
            red[jh][h * 128 + p2 + 1] = acc[h][1];
        }
        __syncthreads();
        for (int idx = t; idx < 1536; idx += 256)
            tmp[(size_t)i * 1536 + idx] = red[0][idx] + red[1][idx] + red[2][idx] + red[3][idx];
        return;
    }

    const int bid  = blockIdx.x - 512;
    const int h    = bid >> 5;
    const int i0   = (bid & 31) << 4;
    const int wid  = t >> 6;
    const int lane = t & 63;
    const int quad = lane >> 4;
    const int col  = lane & 15;
    const int c    = wid * 16 + col;
    const bool cvalid = (c < 56);

    const unsigned short* arow = attn_bf + ((size_t)(h * N_ + i0 + col)) * N_;
    const unsigned short* brow = vcatT + ((size_t)h * 64 + c) * N_;

    f32x4 acc = {0.f, 0.f, 0.f, 0.f};
    #pragma unroll
    for (int kt = 0; kt < 16; ++kt) {
        const int k0 = kt * 32 + quad * 8;
        short8 a = *(const short8*)(arow + k0);
        short8 b;
        if (cvalid) b = *(const short8*)(brow + k0);
        else { b[0]=0;b[1]=0;b[2]=0;b[3]=0;b[4]=0;b[5]=0;b[6]=0;b[7]=0; }
        acc = __builtin_amdgcn_mfma_f32_16x16x32_bf16(a, b, acc, 0, 0, 0);
    }
    #pragma unroll
    for (int r = 0; r < 4; ++r) {
        int i = i0 + quad * 4 + r;
        if (c < 32)       feat[(size_t)i * 1152 + h * 32 + c] = acc[r];
        else if (c < 56)  outpg[((size_t)i * 12 + h) * 24 + (c - 32)] = acc[r];
    }
}

__global__ __launch_bounds__(384) void k_feat(
    const float* __restrict__ tmp, const float* __restrict__ outpg,
    const float* __restrict__ pose_t, const float* __restrict__ pose_r,
    const float* __restrict__ w_pairv, float* __restrict__ feat)
{
    const int i = blockIdx.x;
    const int t = threadIdx.x;
    __shared__ float tsh[1536];
    __shared__ float pg[288];
    __shared__ float pl[288];
    __shared__ float Rsh[9], Tsh[3];

    for (int idx = t; idx < 1536; idx += 384) tsh[idx] = tmp[(size_t)i * 1536 + idx];
    if (t < 288) pg[t] = outpg[i * 288 + t];
    if (t < 9) Rsh[t] = pose_r[i * 9 + t];
    if (t < 3) Tsh[t] = pose_t[i * 3 + t];
    __syncthreads();

    {
        int h = t >> 5;
        const float* ts = tsh + h * 128;
        float acc = 0.f;
        #pragma unroll 4
        for (int p = 0; p < 128; ++p) acc += ts[p] * w_pairv[p * D_ + t];
        feat[(size_t)i * 1152 + 672 + t] = acc;
    }
    if (t < 288) {
        int x3 = t % 3, base = t - x3;
        float g0 = pg[base + 0] - Tsh[0];
        float g1 = pg[base + 1] - Tsh[1];
        float g2 = pg[base + 2] - Tsh[2];
        float v = Rsh[x3*3+0]*g0 + Rsh[x3*3+1]*g1 + Rsh[x3*3+2]*g2;
        pl[t] = v;
        feat[(size_t)i * 1152 + 384 + t] = v;
    }
    __syncthreads();
    if (t < 96) {
        float a = pl[t*3], b = pl[t*3+1], c = pl[t*3+2];
        feat[(size_t)i * 1152 + 1056 + t] = sqrtf(a*a + b*b + c*c);
    }
}

__global__ __launch_bounds__(384) void k_out_part(
    const float* __restrict__ feat, const float* __restrict__ w_out,
    float* __restrict__ part)
{
    const int kc = blockIdx.x >> 6;
    const int i0 = (blockIdx.x & 63) * 8;
    const int t  = threadIdx.x;
    const int k0 = kc * 144;

    float acc[8];
    #pragma unroll
    for (int r = 0; r < 8; ++r) acc[r] = 0.f;

    for (int d = 0; d < 144; d += 4) {
        float4 fr[8];
        #pragma unroll
        for (int r = 0; r < 8; ++r)
            fr[r] = *(const float4*)(feat + (size_t)(i0 + r) * 1152 + k0 + d);
        #pragma unroll
        for (int e = 0; e < 4; ++e) {
            float wv = w_out[(size_t)(k0 + d + e) * D_ + t];
            #pragma unroll
            for (int r = 0; r < 8; ++r)
                acc[r] += ((const float*)&fr[r])[e] * wv;
        }
    }
    #pragma unroll
    for (int r = 0; r < 8; ++r)
        part[((size_t)kc * N_ + i0 + r) * D_ + t] = acc[r];
}

__global__ __launch_bounds__(256) void k_out_red(
    const float* __restrict__ part, const float* __restrict__ b_out,
    float* __restrict__ out)
{
    const int idx = blockIdx.x * 256 + threadIdx.x;
    float s = b_out[idx % D_];
    #pragma unroll
    for (int kc = 0; kc < 8; ++kc) s += part[(size_t)kc * (N_ * D_) + idx];
    out[idx] = s;
}

extern "C" void kernel_launch(void* const* d_in, const int* in_sizes, int n_in,
                              void* d_out, int out_size, void* d_ws, size_t ws_size,
                              hipStream_t stream)
{
    (void)in_sizes; (void)n_in; (void)out_size; (void)ws_size;
    const float* x1d     = (const float*)d_in[0];
    const float* x2d     = (const float*)d_in[1];
    const float* pose_t  = (const float*)d_in[2];
    const float* pose_r  = (const float*)d_in[3];
    const float* bias    = (const float*)d_in[4];
    const float* w_sq    = (const float*)d_in[5];
    const float* w_sk    = (const float*)d_in[6];
    const float* w_sv    = (const float*)d_in[7];
    const float* w_pb    = (const float*)d_in[8];
    const float* w_pq    = (const float*)d_in[9];
    const float* w_pk    = (const float*)d_in[10];
    const float* w_pv    = (const float*)d_in[11];
    const float* tpw     = (const float*)d_in[12];
    const float* w_pairv = (const float*)d_in[13];
    const float* w_out   = (const float*)d_in[14];
    const float* b_out   = (const float*)d_in[15];
    float* out = (float*)d_out;

    float* ws = (float*)d_ws;
    float* qs      = ws;
    float* kst     = qs      + 196608;
    float* qp      = kst     + 196608;
    float* kpt     = qp      + 73728;
    float* pairlog = kpt     + 73728;    // 12*512*512 used
    float* tmp     = pairlog + 3145728;
    float* outpg   = tmp     + 786432;
    float* feat    = outpg   + 147456;
    float* part    = feat    + 589824;   // 1572864 floats
    unsigned short* attn_bf = (unsigned short*)(part + 1572864);  // 12*512*512
    unsigned short* vcatT   = attn_bf + (size_t)12 * N_ * N_;     // 12*64*512

    hipLaunchKernelGGL(k_pair, dim3(2048), dim3(256), 0, stream,
                       x2d, w_pb, pairlog);
    hipLaunchKernelGGL(k_proj, dim3(64, 5), dim3(384), 0, stream,
                       x1d, pose_t, pose_r, w_sq, w_sk, w_sv, w_pq, w_pk, w_pv,
                       qs, kst, qp, kpt, vcatT);
    hipLaunchKernelGGL(k_sp_soft, dim3(12 * 128), dim3(256), 0, stream,
                       qs, kst, qp, kpt, bias, tpw, pairlog, attn_bf);
    hipLaunchKernelGGL(k_mid, dim3(512 + 384), dim3(256), 0, stream,
                       attn_bf, x2d, vcatT, tmp, feat, outpg);
    hipLaunchKernelGGL(k_feat, dim3(N_), dim3(384), 0, stream,
                       tmp, outpg, pose_t, pose_r, w_pairv, feat);
    hipLaunchKernelGGL(k_out_part, dim3(512), dim3(384), 0, stream,
                       feat, w_out, part);
    hipLaunchKernelGGL(k_out_red, dim3(768), dim3(256), 0, stream,
                       part, b_out, out);
}